// Round 6
// baseline (112.482 us; speedup 1.0000x reference)
//
#include <hip/hip_runtime.h>

// 5-level wavedec (filter len 8, pywt 'symmetric'), 4096 rows of 8192 f32.
// Lengths: 8192 -> 4099 -> 2053 -> 1030 -> 518 -> 262
// Out: approx(262) @0, d5(262), d4(518), d3(1030), d2(2053), d1(4099).
//
// R6 design: one WAVE per row, zero LDS, zero __syncthreads. Approx
// intermediates ping-pong through a per-row slice of global scratch (d_ws);
// within-wave RAW ordering on the same buffer is handled by compiler vmcnt
// waits (same mechanism as spills). 1024 blocks = 4 blocks/CU exactly ->
// 16 independent waves/CU, no barrier convoys, no tail rounds.
// Falls back to the R3 barrier/LDS kernel if ws_size is too small.

static constexpr int ROWS = 4096;
static constexpr int N0 = 8192;
static constexpr int L1n = 4099, L2n = 2053, L3n = 1030, L4n = 518, L5n = 262;
static constexpr size_t OFF_D5 = 1073152u;
static constexpr size_t OFF_D4 = 2146304u;
static constexpr size_t OFF_D3 = 4268032u;
static constexpr size_t OFF_D2 = 8486912u;
static constexpr size_t OFF_D1 = 16896000u;

static constexpr int WS_B = 4104;       // float offset of bufB within a row slice
static constexpr int WS_STRIDE = 6160;  // floats per row slice (16B-aligned)
static constexpr size_t WS_NEED = (size_t)ROWS * WS_STRIDE * sizeof(float);

// One DWT level, 4 consecutive outputs per thread from a 16-float window
// (8x float2 loads, 64 FMA). STRIDE = number of cooperating threads.
template <int STRIDE>
__device__ __forceinline__ void dwt_level(
    const float* __restrict__ src, int n, int m,
    const float* __restrict__ h, const float* __restrict__ g,
    float* __restrict__ adst, float* __restrict__ ddst, int tid)
{
    const int ngroups = (m + 3) >> 2;
    const int jmax = (n - 10) >> 3;   // interior iff 1 <= j <= jmax
    for (int j = tid; j < ngroups; j += STRIDE) {
        const int p0 = 4 * j;
        if (j >= 1 && j <= jmax && p0 + 3 < m) {
            // window w[0..15] = src[8j-6 .. 8j+9]
            const float2* __restrict__ s2 =
                reinterpret_cast<const float2*>(src) + (4 * j - 3);
            float w[16];
#pragma unroll
            for (int t = 0; t < 8; ++t) {
                const float2 v = s2[t];
                w[2 * t] = v.x; w[2 * t + 1] = v.y;
            }
            float aa[4], dd[4];
#pragma unroll
            for (int r = 0; r < 4; ++r) {
                float a = 0.f, d = 0.f;
#pragma unroll
                for (int q = 0; q < 8; ++q) {
                    const float v = w[2 * r + 7 - q];   // src[2(p0+r)+1-q]
                    a = fmaf(h[q], v, a);
                    d = fmaf(g[q], v, d);
                }
                aa[r] = a; dd[r] = d;
            }
#pragma unroll
            for (int r = 0; r < 4; ++r) ddst[p0 + r] = dd[r];
#pragma unroll
            for (int r = 0; r < 4; ++r) adst[p0 + r] = aa[r];
        } else {
            // edge groups: branchy symmetric-reflect path (2-3 per level)
#pragma unroll 4
            for (int r = 0; r < 4; ++r) {
                const int pos = p0 + r;
                if (pos >= m) break;
                const int s0 = 2 * pos + 1;
                float a = 0.f, d = 0.f;
#pragma unroll
                for (int q = 0; q < 8; ++q) {
                    int s = s0 - q;
                    int idx = (s < 0) ? (-1 - s) : ((s >= n) ? (2 * n - 1 - s) : s);
                    const float v = src[idx];
                    a = fmaf(h[q], v, a);
                    d = fmaf(g[q], v, d);
                }
                ddst[pos] = d;
                adst[pos] = a;
            }
        }
    }
}

// ---- R6: wave-per-row, global scratch, no barriers ----
__global__ __launch_bounds__(256)
void wavedec5_ws(const float* __restrict__ x,
                 const float* __restrict__ dlo,
                 const float* __restrict__ dhi,
                 float* __restrict__ out,
                 float* __restrict__ ws)
{
    const int lane = threadIdx.x & 63;
    const int row  = (blockIdx.x << 2) + (threadIdx.x >> 6);

    float h[8], g[8];
#pragma unroll
    for (int i = 0; i < 8; ++i) { h[i] = dlo[i]; g[i] = dhi[i]; }

    const float* __restrict__ xr = x + (size_t)row * N0;
    float* bufA = ws + (size_t)row * WS_STRIDE;   // a1 / a3  (4100 fl)
    float* bufB = bufA + WS_B;                    // a2 / a4  (2056 fl)

    dwt_level<64>(xr,   N0,  L1n, h, g, bufA, out + OFF_D1 + (size_t)row * L1n, lane);
    dwt_level<64>(bufA, L1n, L2n, h, g, bufB, out + OFF_D2 + (size_t)row * L2n, lane);
    dwt_level<64>(bufB, L2n, L3n, h, g, bufA, out + OFF_D3 + (size_t)row * L3n, lane);
    dwt_level<64>(bufA, L3n, L4n, h, g, bufB, out + OFF_D4 + (size_t)row * L4n, lane);
    dwt_level<64>(bufB, L4n, L5n, h, g,
                  out + (size_t)row * L5n, out + OFF_D5 + (size_t)row * L5n, lane);
}

// ---- fallback: R3 block/LDS kernel (proven 59 us) ----
__global__ __launch_bounds__(256, 6)
void wavedec5_lds(const float* __restrict__ x,
                  const float* __restrict__ dlo,
                  const float* __restrict__ dhi,
                  float* __restrict__ out)
{
    __shared__ __align__(16) float bufA[4100];
    __shared__ __align__(16) float bufB[2056];

    const int row = blockIdx.x;
    const int tid = threadIdx.x;

    float h[8], g[8];
#pragma unroll
    for (int i = 0; i < 8; ++i) { h[i] = dlo[i]; g[i] = dhi[i]; }

    const float* __restrict__ xr = x + (size_t)row * N0;

    dwt_level<256>(xr,   N0,  L1n, h, g, bufA, out + OFF_D1 + (size_t)row * L1n, tid);
    __syncthreads();
    dwt_level<256>(bufA, L1n, L2n, h, g, bufB, out + OFF_D2 + (size_t)row * L2n, tid);
    __syncthreads();
    dwt_level<256>(bufB, L2n, L3n, h, g, bufA, out + OFF_D3 + (size_t)row * L3n, tid);
    __syncthreads();
    dwt_level<256>(bufA, L3n, L4n, h, g, bufB, out + OFF_D4 + (size_t)row * L4n, tid);
    __syncthreads();
    dwt_level<256>(bufB, L4n, L5n, h, g,
                   out + (size_t)row * L5n, out + OFF_D5 + (size_t)row * L5n, tid);
}

extern "C" void kernel_launch(void* const* d_in, const int* in_sizes, int n_in,
                              void* d_out, int out_size, void* d_ws, size_t ws_size,
                              hipStream_t stream) {
    const float* x   = (const float*)d_in[0];
    const float* dlo = (const float*)d_in[1];
    const float* dhi = (const float*)d_in[2];
    float* out = (float*)d_out;
    if (ws_size >= WS_NEED && d_ws != nullptr) {
        wavedec5_ws<<<ROWS / 4, 256, 0, stream>>>(x, dlo, dhi, out, (float*)d_ws);
    } else {
        wavedec5_lds<<<ROWS, 256, 0, stream>>>(x, dlo, dhi, out);
    }
}

// Round 7
// 63.849 us; speedup vs baseline: 1.7617x; 1.7617x over previous
//
#include <hip/hip_runtime.h>

// 5-level wavedec (filter len 8, pywt 'symmetric'), 4096 rows of 8192 f32.
// Lengths: 8192 -> 4099 -> 2053 -> 1030 -> 518 -> 262
// Out: approx(262) @0, d5(262), d4(518), d3(1030), d2(2053), d1(4099).
//
// R7: two rows per 512-thread block (row = 2*blockIdx + tid/256), shared
// barriers. LDS 48.1 KiB -> 3 blocks/CU x 8 waves = 24 waves/CU (75% occ)
// vs 53% at R3. Inner loop identical to R3's proven 4-outputs/thread
// float2-window form; L1 loop unrolled x2 for global-load MLP.

static constexpr int ROWS = 4096;
static constexpr int N0 = 8192;
static constexpr int L1n = 4099, L2n = 2053, L3n = 1030, L4n = 518, L5n = 262;
static constexpr size_t OFF_D5 = 1073152u;
static constexpr size_t OFF_D4 = 2146304u;
static constexpr size_t OFF_D3 = 4268032u;
static constexpr size_t OFF_D2 = 8486912u;
static constexpr size_t OFF_D1 = 16896000u;

// One DWT level, 4 consecutive outputs per thread from a 16-float window
// (8x float2 loads, 64 FMA). STRIDE = cooperating threads per row.
template <int STRIDE, int UNROLL>
__device__ __forceinline__ void dwt_level(
    const float* __restrict__ src, int n, int m,
    const float* __restrict__ h, const float* __restrict__ g,
    float* __restrict__ adst, float* __restrict__ ddst, int tid)
{
    const int ngroups = (m + 3) >> 2;
    const int jmax = (n - 10) >> 3;   // interior iff 1 <= j <= jmax
#pragma unroll UNROLL
    for (int j = tid; j < ngroups; j += STRIDE) {
        const int p0 = 4 * j;
        if (j >= 1 && j <= jmax && p0 + 3 < m) {
            // window w[0..15] = src[8j-6 .. 8j+9]
            const float2* __restrict__ s2 =
                reinterpret_cast<const float2*>(src) + (4 * j - 3);
            float w[16];
#pragma unroll
            for (int t = 0; t < 8; ++t) {
                const float2 v = s2[t];
                w[2 * t] = v.x; w[2 * t + 1] = v.y;
            }
            float aa[4], dd[4];
#pragma unroll
            for (int r = 0; r < 4; ++r) {
                float a = 0.f, d = 0.f;
#pragma unroll
                for (int q = 0; q < 8; ++q) {
                    const float v = w[2 * r + 7 - q];   // src[2(p0+r)+1-q]
                    a = fmaf(h[q], v, a);
                    d = fmaf(g[q], v, d);
                }
                aa[r] = a; dd[r] = d;
            }
#pragma unroll
            for (int r = 0; r < 4; ++r) ddst[p0 + r] = dd[r];
#pragma unroll
            for (int r = 0; r < 4; ++r) adst[p0 + r] = aa[r];
        } else {
            // edge groups: branchy symmetric-reflect path (2-3 per level)
#pragma unroll 4
            for (int r = 0; r < 4; ++r) {
                const int pos = p0 + r;
                if (pos >= m) break;
                const int s0 = 2 * pos + 1;
                float a = 0.f, d = 0.f;
#pragma unroll
                for (int q = 0; q < 8; ++q) {
                    int s = s0 - q;
                    int idx = (s < 0) ? (-1 - s) : ((s >= n) ? (2 * n - 1 - s) : s);
                    const float v = src[idx];
                    a = fmaf(h[q], v, a);
                    d = fmaf(g[q], v, d);
                }
                ddst[pos] = d;
                adst[pos] = a;
            }
        }
    }
}

__global__ __launch_bounds__(512, 3)
void wavedec5_kernel(const float* __restrict__ x,
                     const float* __restrict__ dlo,
                     const float* __restrict__ dhi,
                     float* __restrict__ out)
{
    __shared__ __align__(16) float bufA[2][4100];  // a1 / a3 per row-half
    __shared__ __align__(16) float bufB[2][2056];  // a2 / a4 per row-half

    const int half = threadIdx.x >> 8;       // 0 or 1
    const int tid  = threadIdx.x & 255;
    const int row  = (blockIdx.x << 1) + half;

    float h[8], g[8];
#pragma unroll
    for (int i = 0; i < 8; ++i) { h[i] = dlo[i]; g[i] = dhi[i]; }

    const float* __restrict__ xr = x + (size_t)row * N0;
    float* __restrict__ bA = bufA[half];
    float* __restrict__ bB = bufB[half];

    // L1: global -> bA, d1 -> global (unroll 2 for global-load MLP)
    dwt_level<256, 2>(xr, N0, L1n, h, g, bA,
                      out + OFF_D1 + (size_t)row * L1n, tid);
    __syncthreads();
    // L2: bA -> bB, d2 -> global
    dwt_level<256, 1>(bA, L1n, L2n, h, g, bB,
                      out + OFF_D2 + (size_t)row * L2n, tid);
    __syncthreads();
    // L3: bB -> bA, d3 -> global
    dwt_level<256, 1>(bB, L2n, L3n, h, g, bA,
                      out + OFF_D3 + (size_t)row * L3n, tid);
    __syncthreads();
    // L4: bA -> bB, d4 -> global
    dwt_level<256, 1>(bA, L3n, L4n, h, g, bB,
                      out + OFF_D4 + (size_t)row * L4n, tid);
    __syncthreads();
    // L5: bB -> approx & d5 straight to global
    dwt_level<256, 1>(bB, L4n, L5n, h, g,
                      out + (size_t)row * L5n,
                      out + OFF_D5 + (size_t)row * L5n, tid);
}

extern "C" void kernel_launch(void* const* d_in, const int* in_sizes, int n_in,
                              void* d_out, int out_size, void* d_ws, size_t ws_size,
                              hipStream_t stream) {
    const float* x   = (const float*)d_in[0];
    const float* dlo = (const float*)d_in[1];
    const float* dhi = (const float*)d_in[2];
    float* out = (float*)d_out;
    wavedec5_kernel<<<ROWS / 2, 512, 0, stream>>>(x, dlo, dhi, out);
}